// Round 13
// baseline (442.847 us; speedup 1.0000x reference)
//
#include <hip/hip_runtime.h>

#define AB 513
#define TD 263169   // 513*513

typedef float f4 __attribute__((ext_vector_type(4)));
typedef float f32x4 __attribute__((ext_vector_type(4)));
typedef short bf16x8 __attribute__((ext_vector_type(8)));
typedef int i32x4 __attribute__((ext_vector_type(4)));
#define GAS __attribute__((address_space(1)))
#define LAS __attribute__((address_space(3)))

// ---------------------------------------------------------------------------
// Kernel 1a: pool over S. Blocks 0..63 = vision bt, 64..127 = audio bt.
// ---------------------------------------------------------------------------
__global__ __launch_bounds__(256) void pool_kernel(
    const float* __restrict__ vx, const float* __restrict__ ax,
    float* __restrict__ pvT, float* __restrict__ paT)
{
    const int isA = (blockIdx.x >= 64);
    const int bt = blockIdx.x & 63;
    const float* x = isA ? ax : vx;
    float* pT = isA ? paT : pvT;
    const int D = isA ? 512 : 768;
    const int nd4 = D >> 2;
    const int tid = threadIdx.x;
    if (tid < nd4) {
        f4 s0 = {0.f, 0.f, 0.f, 0.f}, s1 = s0, s2 = s0, s3 = s0;
        const float* xp = x + (size_t)bt * 64 * D + tid * 4;
        #pragma unroll 4
        for (int ss = 0; ss < 64; ss += 4) {
            s0 += *(const f4*)(xp + (size_t)ss * D);
            s1 += *(const f4*)(xp + (size_t)(ss + 1) * D);
            s2 += *(const f4*)(xp + (size_t)(ss + 2) * D);
            s3 += *(const f4*)(xp + (size_t)(ss + 3) * D);
        }
        const f4 s = ((s0 + s1) + (s2 + s3)) * 0.015625f;
        #pragma unroll
        for (int q = 0; q < 4; ++q) pT[(tid * 4 + q) * 64 + bt] = s[q];
    }
}

// ---------------------------------------------------------------------------
// Kernel 1b: layer1, weight-stationary. Block = 8-h tile; wave = h row.
// ---------------------------------------------------------------------------
__global__ __launch_bounds__(512) void mlp1_kernel(
    const float* __restrict__ pvT, const float* __restrict__ paT,
    const float* __restrict__ vw1, const float* __restrict__ vb1,
    const float* __restrict__ aw1, const float* __restrict__ ab1,
    float* __restrict__ h1vT, float* __restrict__ h1aT)
{
    const int isA = (blockIdx.x >= 64);
    const int D = isA ? 512 : 768;
    const float* pT = isA ? paT : pvT;
    const float* w1 = isA ? aw1 : vw1;
    const float* b1 = isA ? ab1 : vb1;
    float* h1T = isA ? h1aT : h1vT;
    const int tid = threadIdx.x, lane = tid & 63, w = tid >> 6;
    const int h = (blockIdx.x & 63) * 8 + w;
    const float* wr = w1 + (size_t)h * D;

    float a0 = 0.f, a1 = 0.f, a2 = 0.f, a3 = 0.f;
    for (int d = 0; d < D; d += 16) {
        const f4 w0 = *(const f4*)(wr + d);
        const f4 w1v = *(const f4*)(wr + d + 4);
        const f4 w2v = *(const f4*)(wr + d + 8);
        const f4 w3v = *(const f4*)(wr + d + 12);
        #pragma unroll
        for (int q = 0; q < 4; ++q) {
            a0 = fmaf(w0[q],  pT[(d + q) * 64 + lane], a0);
            a1 = fmaf(w1v[q], pT[(d + 4 + q) * 64 + lane], a1);
            a2 = fmaf(w2v[q], pT[(d + 8 + q) * 64 + lane], a2);
            a3 = fmaf(w3v[q], pT[(d + 12 + q) * 64 + lane], a3);
        }
    }
    h1T[h * 64 + lane] = fmaxf((a0 + a1) + (a2 + a3) + b1[h], 0.f);
}

// ---------------------------------------------------------------------------
// Kernel 1c: layer2 (no relu) + trailing ones row.
// ---------------------------------------------------------------------------
__global__ __launch_bounds__(512) void mlp2_kernel(
    const float* __restrict__ h1vT, const float* __restrict__ h1aT,
    const float* __restrict__ vw2, const float* __restrict__ vb2,
    const float* __restrict__ aw2, const float* __restrict__ ab2,
    float* __restrict__ aTout, float* __restrict__ bTout)
{
    const int isA = (blockIdx.x >= 64);
    const float* hT = isA ? h1aT : h1vT;
    const float* w2 = isA ? aw2 : vw2;
    const float* b2 = isA ? ab2 : vb2;
    float* outT = isA ? bTout : aTout;
    const int tid = threadIdx.x, lane = tid & 63, w = tid >> 6;
    const int h = (blockIdx.x & 63) * 8 + w;
    const float* wr = w2 + (size_t)h * 512;

    float a0 = 0.f, a1 = 0.f, a2 = 0.f, a3 = 0.f;
    for (int d = 0; d < 512; d += 16) {
        const f4 w0 = *(const f4*)(wr + d);
        const f4 w1v = *(const f4*)(wr + d + 4);
        const f4 w2v = *(const f4*)(wr + d + 8);
        const f4 w3v = *(const f4*)(wr + d + 12);
        #pragma unroll
        for (int q = 0; q < 4; ++q) {
            a0 = fmaf(w0[q],  hT[(d + q) * 64 + lane], a0);
            a1 = fmaf(w1v[q], hT[(d + 4 + q) * 64 + lane], a1);
            a2 = fmaf(w2v[q], hT[(d + 8 + q) * 64 + lane], a2);
            a3 = fmaf(w3v[q], hT[(d + 12 + q) * 64 + lane], a3);
        }
    }
    outT[h * 64 + lane] = (a0 + a1) + (a2 + a3) + b2[h];
    if ((blockIdx.x & 63) == 0 && tid < 64) outT[512 * 64 + tid] = 1.0f;
}

// ---------------------------------------------------------------------------
// Kernel 1d: split aT into 3 truncated-bf16 levels in MFMA A-fragment order.
// ---------------------------------------------------------------------------
__global__ __launch_bounds__(256) void aprep_kernel(
    const float* __restrict__ aT,   // (513, 64)
    short* __restrict__ aF1, short* __restrict__ aF2, short* __restrict__ aF3)
{
    const int t = blockIdx.x * 256 + threadIdx.x;  // [0, 4096)
    const int l = t & 63, mt = (t >> 6) & 3, kt = t >> 8;
    const int m = mt * 16 + (l & 15);
    const int kbase = kt * 32 + ((l >> 4) << 3);
    const int obase = ((kt * 4 + mt) * 64 + l) * 8;
    #pragma unroll
    for (int i = 0; i < 8; ++i) {
        const float v = aT[(size_t)(kbase + i) * 64 + m];
        const unsigned u = __float_as_uint(v);
        const float r1 = v - __uint_as_float(u & 0xFFFF0000u);
        const unsigned u1 = __float_as_uint(r1);
        const float r2 = r1 - __uint_as_float(u1 & 0xFFFF0000u);
        const unsigned u2 = __float_as_uint(r2);
        aF1[obase + i] = (short)(u >> 16);
        aF2[obase + i] = (short)(u1 >> 16);
        aF3[obase + i] = (short)(u2 >> 16);
    }
}

// ---------------------------------------------------------------------------
// Kernel 2: bilinear via bf16-split MFMA; block = (o, e-half). 2 blocks/CU
// (65.8 KB LDS, <=128 VGPR) -> two independent barrier domains per CU hide
// each other's tile-arrival jitter. Tile = 32 rows x 256 e, row-padded to
// 257 floats (odd stride -> <=2-way LDS banks, free). 1 row = 1 width-16
// DMA, uniform LDS dest. Waves: bh = w>>2 (bt-half -> mt {2bh,2bh+1}),
// ew = w&3 (e-quarter of the half -> 4 nt). acc[2][4] f32x4 = 32 VGPR;
// A-frags single-buffered (24 VGPR), reloaded after COMPUTE (WAR-safe).
// Epoch kt: wait vmcnt(4) [drains stage(kt)+A(kt), leaves stage(kt+1)];
// barrier; COMPUTE(kt); LOADA(kt+1); barrier; STAGE(kt+2).
// Output: PARTIAL sums (no bias/relu) to hp[eh]; fuse2 combines.
// ---------------------------------------------------------------------------
__global__ __launch_bounds__(512, 2) void bilinear_kernel(
    const float* __restrict__ fw1,  // (1024, 263169)
    const float* __restrict__ aT,   // (513, 64)
    const float* __restrict__ bT,   // (513, 64)
    const short* __restrict__ aF1, const short* __restrict__ aF2,
    const short* __restrict__ aF3,
    float* __restrict__ hp0,        // (1024, 64) partial, e-half 0
    float* __restrict__ hp1)        // (1024, 64) partial, e-half 1
{
    __shared__ float lds[2][8224];  // 2 x (32 rows x 257) = 65.8 KB
    const int tid = threadIdx.x;
    const int l = tid & 63, w = tid >> 6;
    const int o = blockIdx.x >> 1, eh = blockIdx.x & 1;
    const float* __restrict__ W = fw1 + (size_t)o * TD;
    const int bh = w >> 2, ew = w & 3;
    const int lq = l >> 4, ln = l & 15;

    // stage rows 4w..4w+3 of tile kt: src per-lane 16B, dst uniform base
    #define STAGE(buf_, kt_)                                                   \
        do {                                                                   \
            _Pragma("unroll")                                                  \
            for (int r_ = 0; r_ < 4; ++r_) {                                   \
                const int row_ = w * 4 + r_;                                   \
                __builtin_amdgcn_global_load_lds(                              \
                    (const GAS unsigned*)(const void*)(W + (size_t)((kt_) * 32 + row_) * AB + 256 * eh + l * 4), \
                    (LAS unsigned*)(void*)(&lds[buf_][row_ * 257]), 16, 0, 0); \
            }                                                                  \
        } while (0)

    #define LOADA(kt_)                                                         \
        do {                                                                   \
            _Pragma("unroll")                                                  \
            for (int mi_ = 0; mi_ < 2; ++mi_) {                                \
                const int fb_ = (((kt_) * 4 + (2 * bh + mi_)) * 64 + l) * 8;   \
                A1[mi_] = *(const bf16x8*)(aF1 + fb_);                         \
                A2[mi_] = *(const bf16x8*)(aF2 + fb_);                         \
                A3[mi_] = *(const bf16x8*)(aF3 + fb_);                         \
            }                                                                  \
        } while (0)

    #define COMPUTE(buf_)                                                      \
        do {                                                                   \
            const float* __restrict__ wb_ = &lds[buf_][0];                     \
            _Pragma("unroll")                                                  \
            for (int nt = 0; nt < 4; ++nt) {                                   \
                const int ecol_ = 64 * ew + nt * 16 + ln;                      \
                unsigned u0[8], u1[8], u2[8];                                  \
                _Pragma("unroll")                                              \
                for (int i = 0; i < 8; ++i) {                                  \
                    const float v = wb_[(lq * 8 + i) * 257 + ecol_];           \
                    u0[i] = __float_as_uint(v);                                \
                    const float r1 = v - __uint_as_float(u0[i] & 0xFFFF0000u); \
                    u1[i] = __float_as_uint(r1);                               \
                    const float r2 = r1 - __uint_as_float(u1[i] & 0xFFFF0000u);\
                    u2[i] = __float_as_uint(r2);                               \
                }                                                              \
                i32x4 p1, p2, p3;                                              \
                _Pragma("unroll")                                              \
                for (int j = 0; j < 4; ++j) {                                  \
                    p1[j] = (int)((u0[2 * j + 1] & 0xFFFF0000u) | (u0[2 * j] >> 16)); \
                    p2[j] = (int)((u1[2 * j + 1] & 0xFFFF0000u) | (u1[2 * j] >> 16)); \
                    p3[j] = (int)((u2[2 * j + 1] & 0xFFFF0000u) | (u2[2 * j] >> 16)); \
                }                                                              \
                const bf16x8 B1 = __builtin_bit_cast(bf16x8, p1);              \
                const bf16x8 B2 = __builtin_bit_cast(bf16x8, p2);              \
                const bf16x8 B3 = __builtin_bit_cast(bf16x8, p3);              \
                _Pragma("unroll")                                              \
                for (int mi = 0; mi < 2; ++mi) {                               \
                    acc[mi][nt] = __builtin_amdgcn_mfma_f32_16x16x32_bf16(A1[mi], B1, acc[mi][nt], 0, 0, 0); \
                    acc[mi][nt] = __builtin_amdgcn_mfma_f32_16x16x32_bf16(A1[mi], B2, acc[mi][nt], 0, 0, 0); \
                    acc[mi][nt] = __builtin_amdgcn_mfma_f32_16x16x32_bf16(A2[mi], B1, acc[mi][nt], 0, 0, 0); \
                    acc[mi][nt] = __builtin_amdgcn_mfma_f32_16x16x32_bf16(A2[mi], B2, acc[mi][nt], 0, 0, 0); \
                    acc[mi][nt] = __builtin_amdgcn_mfma_f32_16x16x32_bf16(A1[mi], B3, acc[mi][nt], 0, 0, 0); \
                    acc[mi][nt] = __builtin_amdgcn_mfma_f32_16x16x32_bf16(A3[mi], B1, acc[mi][nt], 0, 0, 0); \
                }                                                              \
            }                                                                  \
        } while (0)

    f32x4 acc[2][4];
    #pragma unroll
    for (int mi = 0; mi < 2; ++mi)
        #pragma unroll
        for (int nt = 0; nt < 4; ++nt)
            acc[mi][nt] = (f32x4){0.f, 0.f, 0.f, 0.f};
    bf16x8 A1[2], A2[2], A3[2];

    // prologue: queue = [stage0(4), A0(6), stage1(4)]
    STAGE(0, 0);
    LOADA(0);
    STAGE(1, 1);

    #pragma unroll 1
    for (int kt = 0; kt < 14; ++kt) {
        asm volatile("s_waitcnt vmcnt(4)" ::: "memory");  // drain stage(kt)+A(kt)
        __builtin_amdgcn_s_barrier();
        COMPUTE(kt & 1);
        LOADA(kt + 1);                       // reuses A regs (WAR after MFMAs)
        __builtin_amdgcn_s_barrier();
        STAGE(kt & 1, kt + 2);
    }
    // kt = 14: no stage(16)
    asm volatile("s_waitcnt vmcnt(4)" ::: "memory");
    __builtin_amdgcn_s_barrier();
    COMPUTE(0);
    LOADA(15);
    __builtin_amdgcn_s_barrier();
    // kt = 15: full drain
    asm volatile("s_waitcnt vmcnt(0)" ::: "memory");
    __builtin_amdgcn_s_barrier();
    COMPUTE(1);
    // lds[0] dead (all waves past the pre-COMPUTE(15) barrier) -> red scratch

    float* const redM = &lds[0][0];     // [8][32]
    float* const redA = &lds[0][256];   // [8][64]
    float* const redC = &lds[0][768];   // [8][64] (eh==0 only)

    // b-scale + reduce over ln
    float ysum[2][4];
    #pragma unroll
    for (int mi = 0; mi < 2; ++mi)
        #pragma unroll
        for (int r = 0; r < 4; ++r) ysum[mi][r] = 0.f;
    #pragma unroll
    for (int mi = 0; mi < 2; ++mi) {
        const int bt0 = (2 * bh + mi) * 16 + lq * 4;
        #pragma unroll
        for (int nt = 0; nt < 4; ++nt) {
            const int e = 256 * eh + 64 * ew + nt * 16 + ln;
            const f4 bv = *(const f4*)(bT + (size_t)e * 64 + bt0);
            #pragma unroll
            for (int r = 0; r < 4; ++r)
                ysum[mi][r] = fmaf(acc[mi][nt][r], bv[r], ysum[mi][r]);
        }
    }
    #pragma unroll
    for (int mi = 0; mi < 2; ++mi)
        #pragma unroll
        for (int r = 0; r < 4; ++r) {
            float v = ysum[mi][r];
            v += __shfl_xor(v, 1, 64);
            v += __shfl_xor(v, 2, 64);
            v += __shfl_xor(v, 4, 64);
            v += __shfl_xor(v, 8, 64);
            ysum[mi][r] = v;
        }
    if (ln == 0) {
        #pragma unroll
        for (int mi = 0; mi < 2; ++mi)
            #pragma unroll
            for (int r = 0; r < 4; ++r)
                redM[w * 32 + mi * 16 + lq * 4 + r] = ysum[mi][r];
    }

    // row-512 (a == 1): this block's e-half, wave handles 32 e's; lane = bt
    {
        float s = 0.f;
        #pragma unroll 4
        for (int j = 0; j < 32; ++j) {
            const int e = 256 * eh + 32 * w + j;
            s = fmaf(W[(size_t)512 * AB + e], bT[(size_t)e * 64 + l], s);
        }
        redA[w * 64 + l] = s;
    }
    // col-512 (b == 1) + corner: eh == 0 only; wave handles 64 d's
    if (eh == 0) {
        float s = 0.f;
        #pragma unroll 4
        for (int k = 0; k < 64; ++k) {
            const int d = 64 * w + k;
            s = fmaf(aT[(size_t)d * 64 + l], W[(size_t)d * AB + 512], s);
        }
        redC[w * 64 + l] = s;
    }

    __syncthreads();

    if (w == 0) {
        const int bh2 = l >> 5, btl = l & 31;
        float t = 0.f;
        #pragma unroll
        for (int e2 = 0; e2 < 4; ++e2) t += redM[(bh2 * 4 + e2) * 32 + btl];
        #pragma unroll
        for (int w2 = 0; w2 < 8; ++w2) t += redA[w2 * 64 + l];
        if (eh == 0) {
            #pragma unroll
            for (int w2 = 0; w2 < 8; ++w2) t += redC[w2 * 64 + l];
            t += W[(size_t)512 * AB + 512];  // corner (a=b=1)
            hp0[(size_t)o * 64 + l] = t;
        } else {
            hp1[(size_t)o * 64 + l] = t;
        }
    }
    #undef STAGE
    #undef LOADA
    #undef COMPUTE
}

// ---------------------------------------------------------------------------
// Kernel 3a: fused[bt, f] = relu-combine of partials, then @ fw2 + fb2.
//   h[o][bt] = relu(hp0[o][bt] + hp1[o][bt] + fb1[o])
// ---------------------------------------------------------------------------
__global__ __launch_bounds__(512) void fuse2_kernel(
    const float* __restrict__ hp0,   // (1024, 64)
    const float* __restrict__ hp1,   // (1024, 64)
    const float* __restrict__ fb1,   // (1024)
    const float* __restrict__ fw2,   // (512, 1024)
    const float* __restrict__ fb2,   // (512)
    float* __restrict__ fused)       // (64, 512)
{
    const int tid = threadIdx.x, lane = tid & 63, w = tid >> 6;
    #pragma unroll
    for (int k = 0; k < 2; ++k) {
        const int f = blockIdx.x * 16 + w * 2 + k;
        const float* wr = fw2 + (size_t)f * 1024;
        float a0 = 0.f, a1 = 0.f, a2 = 0.f, a3 = 0.f;
        for (int o = 0; o < 1024; o += 16) {
            const f4 w0 = *(const f4*)(wr + o);
            const f4 w1v = *(const f4*)(wr + o + 4);
            const f4 w2v = *(const f4*)(wr + o + 8);
            const f4 w3v = *(const f4*)(wr + o + 12);
            #pragma unroll
            for (int q = 0; q < 4; ++q) {
                const int o0 = o + q, o1 = o + 4 + q, o2 = o + 8 + q, o3 = o + 12 + q;
                const float h0 = fmaxf(hp0[o0 * 64 + lane] + hp1[o0 * 64 + lane] + fb1[o0], 0.f);
                const float h1 = fmaxf(hp0[o1 * 64 + lane] + hp1[o1 * 64 + lane] + fb1[o1], 0.f);
                const float h2 = fmaxf(hp0[o2 * 64 + lane] + hp1[o2 * 64 + lane] + fb1[o2], 0.f);
                const float h3 = fmaxf(hp0[o3 * 64 + lane] + hp1[o3 * 64 + lane] + fb1[o3], 0.f);
                a0 = fmaf(w0[q], h0, a0);
                a1 = fmaf(w1v[q], h1, a1);
                a2 = fmaf(w2v[q], h2, a2);
                a3 = fmaf(w3v[q], h3, a3);
            }
        }
        fused[lane * 512 + f] = (a0 + a1) + (a2 + a3) + fb2[f];
    }
}

// ---------------------------------------------------------------------------
// Kernel 3b: LIF over time. 1024 independent (b, d) chains, T = 32.
// ---------------------------------------------------------------------------
__global__ __launch_bounds__(256) void lif_kernel(
    const float* __restrict__ fused,  // (2, 32, 512)
    float* __restrict__ out)          // (2, 32, 512)
{
    const int idx = blockIdx.x * 256 + threadIdx.x;
    if (idx >= 1024) return;
    const int b = idx >> 9, dd = idx & 511;
    float mem = 0.f;
    for (int t = 0; t < 32; ++t) {
        const size_t off = ((size_t)(b * 32 + t) * 512) + dd;
        mem = 0.9f * mem + fused[off];
        const float s = (mem >= 1.0f) ? 1.0f : 0.0f;
        out[off] = s;
        mem -= s;
    }
}

// ---------------------------------------------------------------------------
extern "C" void kernel_launch(void* const* d_in, const int* in_sizes, int n_in,
                              void* d_out, int out_size, void* d_ws, size_t ws_size,
                              hipStream_t stream) {
    const float* vision = (const float*)d_in[0];
    const float* audio  = (const float*)d_in[1];
    const float* vw1 = (const float*)d_in[2];
    const float* vb1 = (const float*)d_in[3];
    const float* vw2 = (const float*)d_in[4];
    const float* vb2 = (const float*)d_in[5];
    const float* aw1 = (const float*)d_in[6];
    const float* ab1 = (const float*)d_in[7];
    const float* aw2 = (const float*)d_in[8];
    const float* ab2 = (const float*)d_in[9];
    const float* fw1 = (const float*)d_in[10];
    const float* fb1 = (const float*)d_in[11];
    const float* fw2 = (const float*)d_in[12];
    const float* fb2 = (const float*)d_in[13];
    float* out = (float*)d_out;

    float* ws    = (float*)d_ws;
    float* pvT   = ws;                  // 768*64
    float* paT   = pvT + 768 * 64;      // 512*64
    float* h1vT  = paT + 512 * 64;      // 512*64
    float* h1aT  = h1vT + 512 * 64;     // 512*64
    float* aT    = h1aT + 512 * 64;     // 513*64
    float* bT    = aT + AB * 64;        // 513*64
    float* fused = bT + AB * 64;        // 64*512
    short* aF1   = (short*)(fused + 64 * 512);  // 32768 shorts
    short* aF2   = aF1 + 32768;
    short* aF3   = aF2 + 32768;
    float* hp0   = (float*)(aF3 + 32768);       // 1024*64
    float* hp1   = hp0 + 1024 * 64;             // 1024*64

    pool_kernel<<<128, 256, 0, stream>>>(vision, audio, pvT, paT);
    mlp1_kernel<<<128, 512, 0, stream>>>(pvT, paT, vw1, vb1, aw1, ab1, h1vT, h1aT);
    mlp2_kernel<<<128, 512, 0, stream>>>(h1vT, h1aT, vw2, vb2, aw2, ab2, aT, bT);
    aprep_kernel<<<16, 256, 0, stream>>>(aT, aF1, aF2, aF3);
    bilinear_kernel<<<2048, 512, 0, stream>>>(fw1, aT, bT, aF1, aF2, aF3, hp0, hp1);
    fuse2_kernel<<<32, 512, 0, stream>>>(hp0, hp1, fb1, fw2, fb2, fused);
    lif_kernel<<<4, 256, 0, stream>>>(fused, out);
}

// Round 14
// 440.831 us; speedup vs baseline: 1.0046x; 1.0046x over previous
//
#include <hip/hip_runtime.h>

#define AB 513
#define TD 263169   // 513*513

typedef float f4 __attribute__((ext_vector_type(4)));
typedef float f32x4 __attribute__((ext_vector_type(4)));
typedef short bf16x8 __attribute__((ext_vector_type(8)));
typedef int i32x4 __attribute__((ext_vector_type(4)));
#define GAS __attribute__((address_space(1)))
#define LAS __attribute__((address_space(3)))

// ---------------------------------------------------------------------------
// Kernel 1a: pool over S. 320 blocks: 0..191 vision (bt, d-chunk of 256),
// 192..319 audio. Thread = one d; fully coalesced; whole chip busy.
// ---------------------------------------------------------------------------
__global__ __launch_bounds__(256) void pool_kernel(
    const float* __restrict__ vx, const float* __restrict__ ax,
    float* __restrict__ pvT, float* __restrict__ paT)
{
    int b = blockIdx.x;
    const float* x; float* pT; int D, bt, dc;
    if (b < 192) { x = vx; pT = pvT; D = 768; bt = b / 3; dc = b % 3; }
    else { b -= 192; x = ax; pT = paT; D = 512; bt = b >> 1; dc = b & 1; }
    const int d = dc * 256 + threadIdx.x;
    const float* xp = x + (size_t)bt * 64 * D + d;
    float s0 = 0.f, s1 = 0.f, s2 = 0.f, s3 = 0.f;
    #pragma unroll 4
    for (int ss = 0; ss < 64; ss += 4) {
        s0 += xp[(size_t)ss * D];
        s1 += xp[(size_t)(ss + 1) * D];
        s2 += xp[(size_t)(ss + 2) * D];
        s3 += xp[(size_t)(ss + 3) * D];
    }
    pT[d * 64 + bt] = ((s0 + s1) + (s2 + s3)) * 0.015625f;
}

// ---------------------------------------------------------------------------
// Kernel 1b: layer1, weight-stationary. Block = 8-h tile; wave = h row.
// ---------------------------------------------------------------------------
__global__ __launch_bounds__(512) void mlp1_kernel(
    const float* __restrict__ pvT, const float* __restrict__ paT,
    const float* __restrict__ vw1, const float* __restrict__ vb1,
    const float* __restrict__ aw1, const float* __restrict__ ab1,
    float* __restrict__ h1vT, float* __restrict__ h1aT)
{
    const int isA = (blockIdx.x >= 64);
    const int D = isA ? 512 : 768;
    const float* pT = isA ? paT : pvT;
    const float* w1 = isA ? aw1 : vw1;
    const float* b1 = isA ? ab1 : vb1;
    float* h1T = isA ? h1aT : h1vT;
    const int tid = threadIdx.x, lane = tid & 63, w = tid >> 6;
    const int h = (blockIdx.x & 63) * 8 + w;
    const float* wr = w1 + (size_t)h * D;

    float a0 = 0.f, a1 = 0.f, a2 = 0.f, a3 = 0.f;
    for (int d = 0; d < D; d += 16) {
        const f4 w0 = *(const f4*)(wr + d);
        const f4 w1v = *(const f4*)(wr + d + 4);
        const f4 w2v = *(const f4*)(wr + d + 8);
        const f4 w3v = *(const f4*)(wr + d + 12);
        #pragma unroll
        for (int q = 0; q < 4; ++q) {
            a0 = fmaf(w0[q],  pT[(d + q) * 64 + lane], a0);
            a1 = fmaf(w1v[q], pT[(d + 4 + q) * 64 + lane], a1);
            a2 = fmaf(w2v[q], pT[(d + 8 + q) * 64 + lane], a2);
            a3 = fmaf(w3v[q], pT[(d + 12 + q) * 64 + lane], a3);
        }
    }
    h1T[h * 64 + lane] = fmaxf((a0 + a1) + (a2 + a3) + b1[h], 0.f);
}

// ---------------------------------------------------------------------------
// Kernel 1c: layer2 (no relu) + trailing ones row.
// ---------------------------------------------------------------------------
__global__ __launch_bounds__(512) void mlp2_kernel(
    const float* __restrict__ h1vT, const float* __restrict__ h1aT,
    const float* __restrict__ vw2, const float* __restrict__ vb2,
    const float* __restrict__ aw2, const float* __restrict__ ab2,
    float* __restrict__ aTout, float* __restrict__ bTout)
{
    const int isA = (blockIdx.x >= 64);
    const float* hT = isA ? h1aT : h1vT;
    const float* w2 = isA ? aw2 : vw2;
    const float* b2 = isA ? ab2 : vb2;
    float* outT = isA ? bTout : aTout;
    const int tid = threadIdx.x, lane = tid & 63, w = tid >> 6;
    const int h = (blockIdx.x & 63) * 8 + w;
    const float* wr = w2 + (size_t)h * 512;

    float a0 = 0.f, a1 = 0.f, a2 = 0.f, a3 = 0.f;
    for (int d = 0; d < 512; d += 16) {
        const f4 w0 = *(const f4*)(wr + d);
        const f4 w1v = *(const f4*)(wr + d + 4);
        const f4 w2v = *(const f4*)(wr + d + 8);
        const f4 w3v = *(const f4*)(wr + d + 12);
        #pragma unroll
        for (int q = 0; q < 4; ++q) {
            a0 = fmaf(w0[q],  hT[(d + q) * 64 + lane], a0);
            a1 = fmaf(w1v[q], hT[(d + 4 + q) * 64 + lane], a1);
            a2 = fmaf(w2v[q], hT[(d + 8 + q) * 64 + lane], a2);
            a3 = fmaf(w3v[q], hT[(d + 12 + q) * 64 + lane], a3);
        }
    }
    outT[h * 64 + lane] = (a0 + a1) + (a2 + a3) + b2[h];
    if ((blockIdx.x & 63) == 0 && tid < 64) outT[512 * 64 + tid] = 1.0f;
}

// ---------------------------------------------------------------------------
// Kernel 1d: split aT into 3 truncated-bf16 levels, COMBINED chunk layout:
// aFc[((kt*12 + mt*3 + lvl)*64 + l)*8 + i]  (1 KB chunks, DMA-stageable)
// ---------------------------------------------------------------------------
__global__ __launch_bounds__(256) void aprep_kernel(
    const float* __restrict__ aT,   // (513, 64)
    short* __restrict__ aFc)
{
    const int t = blockIdx.x * 256 + threadIdx.x;  // [0, 4096)
    const int l = t & 63, mt = (t >> 6) & 3, kt = t >> 8;
    const int m = mt * 16 + (l & 15);
    const int kbase = kt * 32 + ((l >> 4) << 3);
    const int cb = kt * 12 + mt * 3;
    #pragma unroll
    for (int i = 0; i < 8; ++i) {
        const float v = aT[(size_t)(kbase + i) * 64 + m];
        const unsigned u = __float_as_uint(v);
        const float r1 = v - __uint_as_float(u & 0xFFFF0000u);
        const unsigned u1 = __float_as_uint(r1);
        const float r2 = r1 - __uint_as_float(u1 & 0xFFFF0000u);
        const unsigned u2 = __float_as_uint(r2);
        aFc[((size_t)(cb + 0) * 64 + l) * 8 + i] = (short)(u >> 16);
        aFc[((size_t)(cb + 1) * 64 + l) * 8 + i] = (short)(u1 >> 16);
        aFc[((size_t)(cb + 2) * 64 + l) * 8 + i] = (short)(u2 >> 16);
    }
}

// ---------------------------------------------------------------------------
// Kernel 2: bilinear via bf16-split MFMA. Block = o, 8 waves, 1 block/CU.
// W: 3-deep ring of HALF-tiles (32 rows x 256 e = 32 KB), 32 epochs
// (e = kt*2 + eh). A-frags: staged ONCE per block per kt into a 3-deep
// LDS A-ring (2 DMA/wave, uniform), consumed by ds_read_b128 -- removes
// the 8x-duplicated per-wave global A-loads and purifies the vmcnt FIFO.
// Uniform wait: s_waitcnt vmcnt(6) every epoch (trace: entering epoch e the
// queue is [W(e) 4 | A(kt+1) 2 | W(e+1) 4]; drain 4 -> W(e) done, >=48 KB
// stays in flight). Wave w owns e in {256eh + 32w + [0,32)} per epoch,
// 2 nt per epoch; eh unrolled so acc indexing is compile-time (rule #20).
// Tail epochs dup-stage (identical bytes to live entry: benign).
// ---------------------------------------------------------------------------
__global__ __launch_bounds__(512, 1) void bilinear_kernel(
    const float* __restrict__ fw1,  // (1024, 263169)
    const float* __restrict__ fb1,  // (1024)
    const float* __restrict__ aT,   // (513, 64)
    const float* __restrict__ bT,   // (513, 64)
    const short* __restrict__ aFc,  // combined A-frag chunks
    float* __restrict__ hbufT)      // (1024, 64)
{
    __shared__ float wring[3][8192];   // 96 KB
    __shared__ short aring[3][6144];   // 36 KB (12 chunks x 512 shorts)
    __shared__ float adump[256];       // 1 KB dup-DMA dump

    const int tid = threadIdx.x;
    const int l = tid & 63, w = tid >> 6;
    const int o = blockIdx.x;
    const float* __restrict__ W = fw1 + (size_t)o * TD;
    const int lq = l >> 4, ln = l & 15;

    #define STAGE_W(e_)                                                        \
        do {                                                                   \
            const int ee_ = (e_), kt_ = ee_ >> 1, eh_ = ee_ & 1, en_ = ee_ % 3;\
            _Pragma("unroll")                                                  \
            for (int rr_ = 0; rr_ < 4; ++rr_) {                                \
                const int r_ = w * 4 + rr_;                                    \
                __builtin_amdgcn_global_load_lds(                              \
                    (const GAS unsigned*)(const void*)(W + (size_t)(kt_ * 32 + r_) * AB + 256 * eh_ + l * 4), \
                    (LAS unsigned*)(void*)(&wring[en_][r_ * 256]), 16, 0, 0);  \
            }                                                                  \
        } while (0)

    // 2 DMA per wave, every wave. waves 0-3: chunks {2w, 2w+1};
    // waves 4-7: chunk {4+w} real + 1 dump (identical counts -> uniform FIFO)
    #define STAGE_A(kt_)                                                       \
        do {                                                                   \
            const int kk_ = (kt_), en_ = kk_ % 3;                              \
            const int c0_ = (w < 4) ? (2 * w) : (4 + w);                       \
            const short* s0_ = aFc + ((size_t)kk_ * 12 + c0_) * 512;           \
            __builtin_amdgcn_global_load_lds(                                  \
                (const GAS unsigned*)(const void*)(s0_ + l * 8),               \
                (LAS unsigned*)(void*)(&aring[en_][c0_ * 512]), 16, 0, 0);     \
            if (w < 4) {                                                       \
                const int c1_ = 2 * w + 1;                                     \
                const short* s1_ = aFc + ((size_t)kk_ * 12 + c1_) * 512;       \
                __builtin_amdgcn_global_load_lds(                              \
                    (const GAS unsigned*)(const void*)(s1_ + l * 8),           \
                    (LAS unsigned*)(void*)(&aring[en_][c1_ * 512]), 16, 0, 0); \
            } else {                                                           \
                const short* s1_ = aFc + (size_t)kk_ * 12 * 512;               \
                __builtin_amdgcn_global_load_lds(                              \
                    (const GAS unsigned*)(const void*)(s1_ + l * 2),           \
                    (LAS unsigned*)(void*)(adump), 4, 0, 0);                   \
            }                                                                  \
        } while (0)

    #define LOADA_LDS(kt_)                                                     \
        do {                                                                   \
            const int en_ = (kt_) % 3;                                         \
            _Pragma("unroll")                                                  \
            for (int mt_ = 0; mt_ < 4; ++mt_) {                                \
                A1[mt_] = *(const bf16x8*)&aring[en_][(mt_ * 3 + 0) * 512 + l * 8]; \
                A2[mt_] = *(const bf16x8*)&aring[en_][(mt_ * 3 + 1) * 512 + l * 8]; \
                A3[mt_] = *(const bf16x8*)&aring[en_][(mt_ * 3 + 2) * 512 + l * 8]; \
            }                                                                  \
        } while (0)

    // one epoch's MFMA work; EHC = compile-time eh (rule #20: acc idx static)
    #define COMPUTE(e_, EHC)                                                   \
        do {                                                                   \
            const float* __restrict__ wb_ = &wring[(e_) % 3][0];               \
            _Pragma("unroll")                                                  \
            for (int ntl = 0; ntl < 2; ++ntl) {                                \
                const int col_ = 32 * w + 16 * ntl + ln;                       \
                unsigned u0[8], u1[8], u2[8];                                  \
                _Pragma("unroll")                                              \
                for (int i = 0; i < 8; ++i) {                                  \
                    const float v = wb_[(lq * 8 + i) * 256 + col_];            \
                    u0[i] = __float_as_uint(v);                                \
                    const float r1 = v - __uint_as_float(u0[i] & 0xFFFF0000u); \
                    u1[i] = __float_as_uint(r1);                               \
                    const float r2 = r1 - __uint_as_float(u1[i] & 0xFFFF0000u);\
                    u2[i] = __float_as_uint(r2);                               \
                }                                                              \
                i32x4 p1, p2, p3;                                              \
                _Pragma("unroll")                                              \
                for (int j = 0; j < 4; ++j) {                                  \
                    p1[j] = (int)((u0[2 * j + 1] & 0xFFFF0000u) | (u0[2 * j] >> 16)); \
                    p2[j] = (int)((u1[2 * j + 1] & 0xFFFF0000u) | (u1[2 * j] >> 16)); \
                    p3[j] = (int)((u2[2 * j + 1] & 0xFFFF0000u) | (u2[2 * j] >> 16)); \
                }                                                              \
                const bf16x8 B1 = __builtin_bit_cast(bf16x8, p1);              \
                const bf16x8 B2 = __builtin_bit_cast(bf16x8, p2);              \
                const bf16x8 B3 = __builtin_bit_cast(bf16x8, p3);              \
                _Pragma("unroll")                                              \
                for (int mt = 0; mt < 4; ++mt) {                               \
                    acc[mt][(EHC) * 2 + ntl] = __builtin_amdgcn_mfma_f32_16x16x32_bf16(A1[mt], B1, acc[mt][(EHC) * 2 + ntl], 0, 0, 0); \
                    acc[mt][(EHC) * 2 + ntl] = __builtin_amdgcn_mfma_f32_16x16x32_bf16(A1[mt], B2, acc[mt][(EHC) * 2 + ntl], 0, 0, 0); \
                    acc[mt][(EHC) * 2 + ntl] = __builtin_amdgcn_mfma_f32_16x16x32_bf16(A2[mt], B1, acc[mt][(EHC) * 2 + ntl], 0, 0, 0); \
                    acc[mt][(EHC) * 2 + ntl] = __builtin_amdgcn_mfma_f32_16x16x32_bf16(A2[mt], B2, acc[mt][(EHC) * 2 + ntl], 0, 0, 0); \
                    acc[mt][(EHC) * 2 + ntl] = __builtin_amdgcn_mfma_f32_16x16x32_bf16(A1[mt], B3, acc[mt][(EHC) * 2 + ntl], 0, 0, 0); \
                    acc[mt][(EHC) * 2 + ntl] = __builtin_amdgcn_mfma_f32_16x16x32_bf16(A3[mt], B1, acc[mt][(EHC) * 2 + ntl], 0, 0, 0); \
                }                                                              \
            }                                                                  \
        } while (0)

    f32x4 acc[4][4];
    #pragma unroll
    for (int mt = 0; mt < 4; ++mt)
        #pragma unroll
        for (int nt = 0; nt < 4; ++nt)
            acc[mt][nt] = (f32x4){0.f, 0.f, 0.f, 0.f};
    bf16x8 A1[4], A2[4], A3[4];

    // prologue queue: [W(0) 4 | A(0) 2 | W(1) 4 | A(1) 2]
    STAGE_W(0);
    STAGE_A(0);
    STAGE_W(1);
    STAGE_A(1);

    #pragma unroll 1
    for (int kt = 0; kt < 16; ++kt) {
        const int e0 = 2 * kt;
        // even epoch (eh = 0)
        asm volatile("s_waitcnt vmcnt(6)" ::: "memory");
        __builtin_amdgcn_s_barrier();
        LOADA_LDS(kt);
        COMPUTE(e0, 0);
        __builtin_amdgcn_s_barrier();
        STAGE_W(e0 + 2 <= 31 ? e0 + 2 : 31);
        STAGE_A(kt + 2 <= 15 ? kt + 2 : 15);
        // odd epoch (eh = 1)
        asm volatile("s_waitcnt vmcnt(6)" ::: "memory");
        __builtin_amdgcn_s_barrier();
        COMPUTE(e0 + 1, 1);
        __builtin_amdgcn_s_barrier();
        STAGE_W(e0 + 3 <= 31 ? e0 + 3 : 31);
    }
    asm volatile("s_waitcnt vmcnt(0)" ::: "memory");
    __builtin_amdgcn_s_barrier();   // all DMA done; wring[0] reusable

    // b-scale: e = 256*(ntg>>1) + 32*w + 16*(ntg&1) + ln; bt = mt*16+lq*4+r
    float ysum[4][4];
    #pragma unroll
    for (int mt = 0; mt < 4; ++mt)
        #pragma unroll
        for (int r = 0; r < 4; ++r) ysum[mt][r] = 0.f;
    #pragma unroll
    for (int mt = 0; mt < 4; ++mt) {
        const int bt0 = mt * 16 + lq * 4;
        #pragma unroll
        for (int ntg = 0; ntg < 4; ++ntg) {
            const int e = 256 * (ntg >> 1) + 32 * w + 16 * (ntg & 1) + ln;
            const f4 bv = *(const f4*)(bT + (size_t)e * 64 + bt0);
            #pragma unroll
            for (int r = 0; r < 4; ++r)
                ysum[mt][r] = fmaf(acc[mt][ntg][r], bv[r], ysum[mt][r]);
        }
    }
    #pragma unroll
    for (int mt = 0; mt < 4; ++mt)
        #pragma unroll
        for (int r = 0; r < 4; ++r) {
            float v = ysum[mt][r];
            v += __shfl_xor(v, 1, 64);
            v += __shfl_xor(v, 2, 64);
            v += __shfl_xor(v, 4, 64);
            v += __shfl_xor(v, 8, 64);
            ysum[mt][r] = v;
        }
    if (ln == 0) {
        #pragma unroll
        for (int mt = 0; mt < 4; ++mt)
            #pragma unroll
            for (int r = 0; r < 4; ++r)
                wring[0][w * 64 + mt * 16 + lq * 4 + r] = ysum[mt][r];
    }

    // aux: e=512 col (b==1) + d=512 row (a==1); wave covers [64w, 64w+64)
    {
        const int we0 = w * 64;
        float s0 = 0.f, s1 = 0.f, s2 = 0.f, s3 = 0.f;
        #pragma unroll 4
        for (int k = 0; k < 64; k += 4) {
            s0 = fmaf(aT[(size_t)(we0 + k) * 64 + l], W[(size_t)(we0 + k) * AB + 512], s0);
            s1 = fmaf(aT[(size_t)(we0 + k + 1) * 64 + l], W[(size_t)(we0 + k + 1) * AB + 512], s1);
            s2 = fmaf(aT[(size_t)(we0 + k + 2) * 64 + l], W[(size_t)(we0 + k + 2) * AB + 512], s2);
            s3 = fmaf(aT[(size_t)(we0 + k + 3) * 64 + l], W[(size_t)(we0 + k + 3) * AB + 512], s3);
        }
        #pragma unroll 4
        for (int k = 0; k < 64; k += 4) {
            s0 = fmaf(W[(size_t)512 * AB + we0 + k], bT[(size_t)(we0 + k) * 64 + l], s0);
            s1 = fmaf(W[(size_t)512 * AB + we0 + k + 1], bT[(size_t)(we0 + k + 1) * 64 + l], s1);
            s2 = fmaf(W[(size_t)512 * AB + we0 + k + 2], bT[(size_t)(we0 + k + 2) * 64 + l], s2);
            s3 = fmaf(W[(size_t)512 * AB + we0 + k + 3], bT[(size_t)(we0 + k + 3) * 64 + l], s3);
        }
        wring[0][512 + w * 64 + l] = (s0 + s1) + (s2 + s3);
    }

    __syncthreads();

    if (w == 0) {
        float t2 = 0.f;
        #pragma unroll
        for (int k = 0; k < 8; ++k)
            t2 += wring[0][k * 64 + l] + wring[0][512 + k * 64 + l];
        t2 += W[(size_t)512 * AB + 512] + fb1[o];  // corner (a=b=1)
        hbufT[(size_t)o * 64 + l] = fmaxf(t2, 0.f);
    }
    #undef STAGE_W
    #undef STAGE_A
    #undef LOADA_LDS
    #undef COMPUTE
}

// ---------------------------------------------------------------------------
// Kernel 3a: fused[bt, f] = h[bt, :] @ fw2[f, :] + fb2[f].
// ---------------------------------------------------------------------------
__global__ __launch_bounds__(512) void fuse2_kernel(
    const float* __restrict__ hbufT,  // (1024, 64)
    const float* __restrict__ fw2,    // (512, 1024)
    const float* __restrict__ fb2,    // (512)
    float* __restrict__ fused)        // (64, 512)
{
    const int tid = threadIdx.x, lane = tid & 63, w = tid >> 6;
    #pragma unroll
    for (int k = 0; k < 2; ++k) {
        const int f = blockIdx.x * 16 + w * 2 + k;
        const float* wr = fw2 + (size_t)f * 1024;
        float a0 = 0.f, a1 = 0.f, a2 = 0.f, a3 = 0.f;
        for (int o = 0; o < 1024; o += 16) {
            const f4 w0 = *(const f4*)(wr + o);
            const f4 w1v = *(const f4*)(wr + o + 4);
            const f4 w2v = *(const f4*)(wr + o + 8);
            const f4 w3v = *(const f4*)(wr + o + 12);
            #pragma unroll
            for (int q = 0; q < 4; ++q) {
                a0 = fmaf(w0[q],  hbufT[(o + q) * 64 + lane], a0);
                a1 = fmaf(w1v[q], hbufT[(o + 4 + q) * 64 + lane], a1);
                a2 = fmaf(w2v[q], hbufT[(o + 8 + q) * 64 + lane], a2);
                a3 = fmaf(w3v[q], hbufT[(o + 12 + q) * 64 + lane], a3);
            }
        }
        fused[lane * 512 + f] = (a0 + a1) + (a2 + a3) + fb2[f];
    }
}

// ---------------------------------------------------------------------------
// Kernel 3b: LIF over time. 1024 independent (b, d) chains, T = 32.
// ---------------------------------------------------------------------------
__global__ __launch_bounds__(256) void lif_kernel(
    const float* __restrict__ fused,  // (2, 32, 512)
    float* __restrict__ out)          // (2, 32, 512)
{
    const int idx = blockIdx.x * 256 + threadIdx.x;
    if (idx >= 1024) return;
    const int b = idx >> 9, dd = idx & 511;
    float mem = 0.f;
    for (int t = 0; t < 32; ++t) {
        const size_t off = ((size_t)(b * 32 + t) * 512) + dd;
        mem = 0.9f * mem + fused[off];
        const float s = (mem >= 1.0f) ? 1.0f : 0.0f;
        out[off] = s;
        mem -= s;
    }
}

// ---------------------------------------------------------------------------
extern "C" void kernel_launch(void* const* d_in, const int* in_sizes, int n_in,
                              void* d_out, int out_size, void* d_ws, size_t ws_size,
                              hipStream_t stream) {
    const float* vision = (const float*)d_in[0];
    const float* audio  = (const float*)d_in[1];
    const float* vw1 = (const float*)d_in[2];
    const float* vb1 = (const float*)d_in[3];
    const float* vw2 = (const float*)d_in[4];
    const float* vb2 = (const float*)d_in[5];
    const float* aw1 = (const float*)d_in[6];
    const float* ab1 = (const float*)d_in[7];
    const float* aw2 = (const float*)d_in[8];
    const float* ab2 = (const float*)d_in[9];
    const float* fw1 = (const float*)d_in[10];
    const float* fb1 = (const float*)d_in[11];
    const float* fw2 = (const float*)d_in[12];
    const float* fb2 = (const float*)d_in[13];
    float* out = (float*)d_out;

    float* ws    = (float*)d_ws;
    float* pvT   = ws;                  // 768*64
    float* paT   = pvT + 768 * 64;      // 512*64
    float* h1vT  = paT + 512 * 64;      // 512*64
    float* h1aT  = h1vT + 512 * 64;     // 512*64
    float* aT    = h1aT + 512 * 64;     // 513*64
    float* bT    = aT + AB * 64;        // 513*64
    float* hbufT = bT + AB * 64;        // 1024*64
    float* fused = hbufT + 1024 * 64;   // 64*512
    short* aFc   = (short*)(fused + 64 * 512);  // 16*12*512 = 98304 shorts

    pool_kernel<<<320, 256, 0, stream>>>(vision, audio, pvT, paT);
    mlp1_kernel<<<128, 512, 0, stream>>>(pvT, paT, vw1, vb1, aw1, ab1, h1vT, h1aT);
    mlp2_kernel<<<128, 512, 0, stream>>>(h1vT, h1aT, vw2, vb2, aw2, ab2, aT, bT);
    aprep_kernel<<<16, 256, 0, stream>>>(aT, aFc);
    bilinear_kernel<<<1024, 512, 0, stream>>>(fw1, fb1, aT, bT, aFc, hbufT);
    fuse2_kernel<<<32, 512, 0, stream>>>(hbufT, fw2, fb2, fused);
    lif_kernel<<<4, 256, 0, stream>>>(fused, out);
}